// Round 3
// baseline (328.773 us; speedup 1.0000x reference)
//
#include <hip/hip_runtime.h>

typedef __bf16 bf16x8 __attribute__((ext_vector_type(8)));
typedef __bf16 bf16x4 __attribute__((ext_vector_type(4)));
typedef float f32x4 __attribute__((ext_vector_type(4)));

#define DEV __device__ __forceinline__

DEV f32x4 mfma16(bf16x8 a, bf16x8 b, f32x4 c) {
    return __builtin_amdgcn_mfma_f32_16x16x32_bf16(a, b, c, 0, 0, 0);
}

DEV void async16(const void* g, void* l) {
    __builtin_amdgcn_global_load_lds((__attribute__((address_space(1))) void*)g,
                                     (__attribute__((address_space(3))) void*)l, 16, 0, 0);
}

// compiler-only ordering fence (no instruction emitted)
#define LDS_FENCE() asm volatile("" ::: "memory")
// raw barrier / counted vmcnt (never drain to 0 inside the K-loop)
#define BARRIER() asm volatile("s_barrier" ::: "memory")
#define VMCNT(n) asm volatile("s_waitcnt vmcnt(" #n ")" ::: "memory")

// ---------------- cast x (f32 -> bf16), 8 elems/thread ----------------
__global__ __launch_bounds__(256) void cast_x_kernel(const float4* __restrict__ in,
                                                     bf16x8* __restrict__ out) {
    int i = blockIdx.x * 256 + threadIdx.x;
    float4 a = in[2 * i], b = in[2 * i + 1];
    bf16x8 o;
    o[0] = (__bf16)a.x; o[1] = (__bf16)a.y; o[2] = (__bf16)a.z; o[3] = (__bf16)a.w;
    o[4] = (__bf16)b.x; o[5] = (__bf16)b.y; o[6] = (__bf16)b.z; o[7] = (__bf16)b.w;
    out[i] = o;
}

// ------------- transpose + cast: src (R x C f32) -> dst (C x R bf16) -------------
__global__ void transpose_cast_kernel(const float* __restrict__ src,
                                      __bf16* __restrict__ dst, int R, int C) {
    __shared__ float tile[32][33];
    int tx = threadIdx.x, ty = threadIdx.y;
    int c0 = blockIdx.x * 32, r0 = blockIdx.y * 32;
#pragma unroll
    for (int j = 0; j < 4; ++j)
        tile[ty + j * 8][tx] = src[(size_t)(r0 + ty + j * 8) * C + c0 + tx];
    __syncthreads();
#pragma unroll
    for (int j = 0; j < 4; ++j)
        dst[(size_t)(c0 + ty + j * 8) * R + r0 + tx] = (__bf16)tile[tx][ty + j * 8];
}

// ---------------- mask nonzero flags: flags[g] = any(mask[g] != 0) ----------------
__global__ __launch_bounds__(256) void mask_flag_kernel(const float* __restrict__ mask,
                                                        int* __restrict__ flags) {
    int g = blockIdx.x;
    const float4* m4 = (const float4*)(mask + (size_t)g * 32768);
    int any = 0;
    for (int i = threadIdx.x; i < 8192; i += 256) {
        float4 v = m4[i];
        any |= (v.x != 0.f) | (v.y != 0.f) | (v.z != 0.f) | (v.w != 0.f);
    }
    any = __any(any) ? 1 : 0;
    __shared__ int s;
    if (threadIdx.x == 0) s = 0;
    __syncthreads();
    if ((threadIdx.x & 63) == 0 && any) atomicOr(&s, 1);
    __syncthreads();
    if (threadIdx.x == 0) flags[g] = s;
}

// stage one 16-KiB unit (matrix X, K-half of K-tile): 2 loads/thread.
// dest chunk d = i*512+tid (lane-linear, as global_load_lds requires);
// content at dest chunk d (r=d>>2, dc=d&3) is logical chunk cc = dc ^ ((r>>2)&3)
// -> pre-swizzled GLOBAL source, LDS stays linear. koff = kt*64 + h*32 (elems).
DEV void stage_unit(const __bf16* __restrict__ Gbase, __bf16* unit, int tid, int koff) {
#pragma unroll
    for (int i = 0; i < 2; ++i) {
        int d = i * 512 + tid;
        int r = d >> 2;
        int cc = (d & 3) ^ ((r >> 2) & 3);
        async16(Gbase + (size_t)r * 512 + koff + cc * 8, unit + d * 8);
    }
}

// ---------------- GEMM: C = A[M,512] * Bt[N,512]^T + bias ----------------
// 256x256 tile, BK=64, 8 waves (2M x 4N). Per-phase schedule (T3+T4+T5):
// LDS As/Bs[par][khalf][256x32] -- each (matrix, khalf) unit is a contiguous
// 16 KiB block, swizzled chunk p = c ^ ((row>>2)&3) within 64-B rows (reads
// sweep every 16B chunk exactly once per wave -> conflict-free). 4 phases per
// K-tile {(mh,ks)}: [ds_reads | stage 1 unit | barrier | 16 MFMA | vmcnt | barrier].
// ORDERING INVARIANT (the round-2 race fix): the counted vmcnt covering the
// units read in phase p sits at the END of phase p-1, BEFORE its closing
// barrier -- so every wave's wait precedes the barrier the reader crosses.
// Steady state holds 8-12 loads in flight; tail drains 8 -> 4 -> 0.
// mode 0: write bf16 qkv relayout [type][nh][32768][32]   (N=1536)
// mode 1: write f32 row-major C[M][N]
__global__ __launch_bounds__(512, 2) void gemm256(const __bf16* __restrict__ A,
                                                  const __bf16* __restrict__ Bt,
                                                  const float* __restrict__ bias0,
                                                  const float* __restrict__ bias1,
                                                  void* __restrict__ Cout, int N, int mode) {
    __shared__ __bf16 As[2][2][256 * 32];
    __shared__ __bf16 Bs[2][2][256 * 32];
    const int tid = threadIdx.x;
    const int bm = blockIdx.x, bn = blockIdx.y;
    const int lane = tid & 63, wv = tid >> 6;
    const int quad = lane >> 4, l16 = lane & 15;
    const int wm = (wv >> 2) * 128, wn = (wv & 3) * 64;
    const __bf16* Abase = A + (size_t)bm * 256 * 512;
    const __bf16* Bbase = Bt + (size_t)bn * 256 * 512;

    f32x4 acc[8][4] = {};

    // prologue: units A(0,0),B(0,0),A(0,1),B(0,1),A(1,0),B(1,0)  (12 loads)
    stage_unit(Abase, &As[0][0][0], tid, 0 * 64 + 0);
    stage_unit(Bbase, &Bs[0][0][0], tid, 0 * 64 + 0);
    stage_unit(Abase, &As[0][1][0], tid, 0 * 64 + 32);
    stage_unit(Bbase, &Bs[0][1][0], tid, 0 * 64 + 32);
    stage_unit(Abase, &As[1][0][0], tid, 1 * 64 + 0);
    stage_unit(Bbase, &Bs[1][0][0], tid, 1 * 64 + 0);
    VMCNT(8);   // A(0,0), B(0,0) landed
    BARRIER();

#pragma unroll
    for (int kt = 0; kt < 8; ++kt) {
        const int par = kt & 1;
        bf16x8 bfm[4];
#pragma unroll
        for (int ph = 0; ph < 4; ++ph) {
            const int mh = ph & 1, ks = ph >> 1;
            // ds-load register subtiles (4 A-frags; +4 B-frags at ks start)
            bf16x8 af[4];
            if (mh == 0) {
#pragma unroll
                for (int t = 0; t < 4; ++t) {
                    int rb = wn + t * 16 + l16;
                    bfm[t] = *(const bf16x8*)&Bs[par][ks][rb * 32 + ((quad ^ ((rb >> 2) & 3)) << 3)];
                }
            }
#pragma unroll
            for (int t = 0; t < 4; ++t) {
                int ra = wm + mh * 64 + t * 16 + l16;
                af[t] = *(const bf16x8*)&As[par][ks][ra * 32 + ((quad ^ ((ra >> 2) & 3)) << 3)];
            }
            // stage exactly one unit per phase (slot's last reader finished a
            // full barrier-pair earlier -- overwrite safe)
            if (ph == 0 && kt + 1 < 8) stage_unit(Abase, &As[par ^ 1][1][0], tid, (kt + 1) * 64 + 32);
            if (ph == 1 && kt + 1 < 8) stage_unit(Bbase, &Bs[par ^ 1][1][0], tid, (kt + 1) * 64 + 32);
            if (ph == 2 && kt + 2 < 8) stage_unit(Abase, &As[par][0][0], tid, (kt + 2) * 64 + 0);
            if (ph == 3 && kt + 2 < 8) stage_unit(Bbase, &Bs[par][0][0], tid, (kt + 2) * 64 + 0);
            BARRIER();
            __builtin_amdgcn_s_setprio(1);
#pragma unroll
            for (int mt = 0; mt < 4; ++mt)
#pragma unroll
                for (int nt = 0; nt < 4; ++nt)
                    acc[mh * 4 + mt][nt] = mfma16(af[mt], bfm[nt], acc[mh * 4 + mt][nt]);
            __builtin_amdgcn_s_setprio(0);
            // counted wait for the NEXT phase's units, before the barrier the
            // next phase's readers will cross:
            //   end ph1: A(kt,1),B(kt,1)   end ph3: A(kt+1,0),B(kt+1,0)
            if (ph == 1) { if (kt < 7) { VMCNT(8); } else { VMCNT(0); } }
            if (ph == 3) { if (kt < 6) { VMCNT(8); } else if (kt == 6) { VMCNT(4); } }
            BARRIER();
        }
    }

    // acc[a] covers rows (a>>2)*64 + (a&3)*16 of the wave's 128-row strip
#pragma unroll
    for (int nt = 0; nt < 4; ++nt) {
        int ng = bn * 256 + wn + nt * 16 + l16;
        float bias = (ng < 512) ? bias0[ng] : bias1[ng - 512];
        if (mode == 0) {
            int type = ng >> 9, nhh = (ng >> 5) & 15, ch = ng & 31;
            __bf16* dst = (__bf16*)Cout + (size_t)type * 16777216 + (size_t)nhh * 1048576 + ch;
#pragma unroll
            for (int mt = 0; mt < 8; ++mt)
#pragma unroll
                for (int r = 0; r < 4; ++r) {
                    int mg = bm * 256 + wm + (mt >> 2) * 64 + (mt & 3) * 16 + quad * 4 + r;
                    dst[(size_t)mg * 32] = (__bf16)(acc[mt][nt][r] + bias);
                }
        } else {
#pragma unroll
            for (int mt = 0; mt < 8; ++mt)
#pragma unroll
                for (int r = 0; r < 4; ++r) {
                    int mg = bm * 256 + wm + (mt >> 2) * 64 + (mt & 3) * 16 + quad * 4 + r;
                    ((float*)Cout)[(size_t)mg * N + ng] = acc[mt][nt][r] + bias;
                }
        }
    }
}

// ---------------- fused window attention, one workgroup per (b, g, nh) ----------------
// qkv layout: [type(q/k/v)][nh][row = (b*64+h)*64+w][32 ch]  (bf16)
// N=128 queries, 2N=256 keys (key = roll*128 + ws1*16 + ws2)
#define ATT_SCALE 0.17677669529663687f

__global__ __launch_bounds__(256, 4) void attn_kernel(const __bf16* __restrict__ qkv,
                                                      const float* __restrict__ peq,
                                                      const float* __restrict__ pekv,
                                                      const float* __restrict__ mask,
                                                      const int* __restrict__ mflags,
                                                      __bf16* __restrict__ oatt) {
    // LDS 38400 B -> 4 blocks/CU:
    //   [0,16384)      Ks: swizzled [256 keys][32 ch], chunk p = c ^ ((key>>1)&3)
    //   [16384,33280)  Vt[32][264]
    //   [33280,38400)  Ps: 4 per-wave slices of [16 rows][40]
    __shared__ __align__(16) char smem[38400];
    __bf16* Ks = (__bf16*)smem;
    __bf16* Vt = (__bf16*)(smem + 16384);
    __bf16* Ps = (__bf16*)(smem + 33280);

    const int tid = threadIdx.x;
    // XCD swizzle: 16 nh-siblings (same qkv rows) -> same XCD; XCD x <- batch x
    const int bid = ((blockIdx.x & 7) << 9) | (blockIdx.x >> 3);
    const int b = bid >> 9;
    const int g = (bid >> 4) & 31;
    const int nh = bid & 15;
    const int gh = g >> 2, gw = g & 3;
    const int lane = tid & 63, wv = tid >> 6;
    const int quad = lane >> 4, l16 = lane & 15;

    const __bf16* qq = qkv + (size_t)nh * 1048576;
    const __bf16* kkp = qkv + 16777216 + (size_t)nh * 1048576;
    const __bf16* vvp = qkv + 33554432 + (size_t)nh * 1048576;

    // ---- stage K with rotary + roll into swizzled layout ----
#pragma unroll
    for (int it = 0; it < 4; ++it) {
        int item = it * 256 + tid;
        int ko = item >> 2, c8 = item & 3;
        int roll = ko >> 7, n = ko & 127;
        int h = (gh * 8 + (n >> 4) + (roll ? 60 : 4)) & 63;  // roll0:+4, roll1:-4 (mod 64)
        int w = gw * 16 + (n & 15);
        int row = (b * 64 + h) * 64 + w;
        bf16x8 v = *(const bf16x8*)(kkp + (size_t)row * 32 + c8 * 8);
        int pidx = (g * 256 + ko) * 16 + c8 * 4;
        float4 c4 = *(const float4*)(pekv + pidx);
        float4 s4 = *(const float4*)(pekv + 131072 + pidx);
        float cs[4] = {c4.x, c4.y, c4.z, c4.w}, sn[4] = {s4.x, s4.y, s4.z, s4.w};
        bf16x4 lo, hi;
#pragma unroll
        for (int j = 0; j < 4; ++j) {
            float k0 = (float)v[2 * j], k1 = (float)v[2 * j + 1];
            lo[j] = (__bf16)(k0 * cs[j] - k1 * sn[j]);
            hi[j] = (__bf16)(k1 * cs[j] + k0 * sn[j]);
        }
        int sw = (ko >> 1) & 3;
        int base = ko * 32, off = (c8 & 1) * 4;
        *(bf16x4*)&Ks[base + (((c8 >> 1) ^ sw) << 3) + off]       = lo;
        *(bf16x4*)&Ks[base + (((2 + (c8 >> 1)) ^ sw) << 3) + off] = hi;
    }
    // ---- stage V transposed (Vt[ch][key]) ----
#pragma unroll
    for (int it = 0; it < 4; ++it) {
        int ko = tid;
        int roll = ko >> 7, n = ko & 127;
        int h = (gh * 8 + (n >> 4) + (roll ? 60 : 4)) & 63;
        int w = gw * 16 + (n & 15);
        int row = (b * 64 + h) * 64 + w;
        bf16x8 v = *(const bf16x8*)(vvp + (size_t)row * 32 + it * 8);
#pragma unroll
        for (int j = 0; j < 8; ++j)
            Vt[(it * 8 + j) * 264 + ko] = v[j];
    }

    // ---- Q A-fragments straight into registers (overlaps staging latency) ----
    bf16x8 aq[2];
    {
        const int halfsel = quad & 1;      // raw channel half
        const bool hi_half = quad >= 2;    // rotary output half
#pragma unroll
        for (int rt = 0; rt < 2; ++rt) {
            int n = wv * 32 + rt * 16 + l16;
            int h = gh * 8 + (n >> 4), w = gw * 16 + (n & 15);
            int row = (b * 64 + h) * 64 + w;
            const __bf16* qp = qq + (size_t)row * 32 + halfsel * 16;
            bf16x8 rA = *(const bf16x8*)qp;
            bf16x8 rB = *(const bf16x8*)(qp + 8);
            int pb = (g * 128 + n) * 16 + halfsel * 8;
            float4 ca = *(const float4*)(peq + pb);
            float4 cb = *(const float4*)(peq + pb + 4);
            float4 sa = *(const float4*)(peq + 65536 + pb);
            float4 sb = *(const float4*)(peq + 65536 + pb + 4);
            float cc[8] = {ca.x, ca.y, ca.z, ca.w, cb.x, cb.y, cb.z, cb.w};
            float ss[8] = {sa.x, sa.y, sa.z, sa.w, sb.x, sb.y, sb.z, sb.w};
#pragma unroll
            for (int j = 0; j < 8; ++j) {
                float q0 = (float)(j < 4 ? rA[2 * j] : rB[2 * (j - 4)]);
                float q1 = (float)(j < 4 ? rA[2 * j + 1] : rB[2 * (j - 4) + 1]);
                float r = hi_half ? (q1 * cc[j] + q0 * ss[j]) : (q0 * cc[j] - q1 * ss[j]);
                aq[rt][j] = (__bf16)(r * ATT_SCALE);
            }
        }
    }
    __syncthreads();  // the ONLY barrier

    // ---- barrier-free flash loop: 8 chunks x 32 keys ----
    f32x4 o00 = {}, o01 = {}, o10 = {}, o11 = {};
    f32x4 rs0 = {}, rs1 = {};
    const bool use_mask = mflags[g] != 0;
    const float* mg = mask + (size_t)g * 32768;
    __bf16* Pw = Ps + wv * 640;           // private [16][40] slice
    const int arow = l16 * 40 + quad * 8; // A-frag read address (elems)

#pragma unroll 2
    for (int ch = 0; ch < 8; ++ch) {
        bf16x8 vb0 = *(const bf16x8*)&Vt[l16 * 264 + ch * 32 + quad * 8];
        bf16x8 vb1 = *(const bf16x8*)&Vt[(16 + l16) * 264 + ch * 32 + quad * 8];
        f32x4 z = {0.f, 0.f, 0.f, 0.f};
        int key0 = ch * 32 + l16, key1 = key0 + 16;
        bf16x8 bk0 = *(const bf16x8*)&Ks[key0 * 32 + ((quad ^ ((key0 >> 1) & 3)) << 3)];
        bf16x8 bk1 = *(const bf16x8*)&Ks[key1 * 32 + ((quad ^ ((key1 >> 1) & 3)) << 3)];
        f32x4 s00 = mfma16(aq[0], bk0, z), s01 = mfma16(aq[0], bk1, z);
        f32x4 s10 = mfma16(aq[1], bk0, z), s11 = mfma16(aq[1], bk1, z);

        if (use_mask) {
#pragma unroll
            for (int r = 0; r < 4; ++r) {
                int r0 = (wv * 32 + quad * 4 + r) * 256 + ch * 32 + l16;
                int r1 = (wv * 32 + 16 + quad * 4 + r) * 256 + ch * 32 + l16;
                s00[r] += mg[r0];      s01[r] += mg[r0 + 16];
                s10[r] += mg[r1];      s11[r] += mg[r1 + 16];
            }
        }
#pragma unroll
        for (int r = 0; r < 4; ++r) {
            s00[r] = __expf(s00[r]); s01[r] = __expf(s01[r]);
            s10[r] = __expf(s10[r]); s11[r] = __expf(s11[r]);
            rs0[r] += s00[r] + s01[r];
            rs1[r] += s10[r] + s11[r];
        }
        // P(rt0) -> own slice -> A-frag; in-order per-wave DS pipe makes this safe
#pragma unroll
        for (int r = 0; r < 4; ++r) {
            Pw[(quad * 4 + r) * 40 + l16]      = (__bf16)s00[r];
            Pw[(quad * 4 + r) * 40 + 16 + l16] = (__bf16)s01[r];
        }
        LDS_FENCE();
        bf16x8 a0 = *(const bf16x8*)&Pw[arow];
        LDS_FENCE();
#pragma unroll
        for (int r = 0; r < 4; ++r) {
            Pw[(quad * 4 + r) * 40 + l16]      = (__bf16)s10[r];
            Pw[(quad * 4 + r) * 40 + 16 + l16] = (__bf16)s11[r];
        }
        LDS_FENCE();
        bf16x8 a1 = *(const bf16x8*)&Pw[arow];
        LDS_FENCE();
        o00 = mfma16(a0, vb0, o00); o01 = mfma16(a0, vb1, o01);
        o10 = mfma16(a1, vb0, o10); o11 = mfma16(a1, vb1, o11);
    }

    // ---- finish row sums (16-lane butterfly) and normalize ----
#pragma unroll
    for (int off = 1; off < 16; off <<= 1) {
#pragma unroll
        for (int r = 0; r < 4; ++r) {
            rs0[r] += __shfl_xor(rs0[r], off);
            rs1[r] += __shfl_xor(rs1[r], off);
        }
    }
#pragma unroll
    for (int r = 0; r < 4; ++r) { rs0[r] = 1.f / rs0[r]; rs1[r] = 1.f / rs1[r]; }

    // ---- write O straight into (b,h,w, nh*32+c) layout (bf16) ----
#pragma unroll
    for (int r = 0; r < 4; ++r) {
        {
            int rown = wv * 32 + quad * 4 + r;
            int h = gh * 8 + (rown >> 4), w = gw * 16 + (rown & 15);
            size_t base = ((size_t)(b * 64 + h) * 64 + w) * 512 + nh * 32;
            oatt[base + l16]      = (__bf16)(o00[r] * rs0[r]);
            oatt[base + 16 + l16] = (__bf16)(o01[r] * rs0[r]);
        }
        {
            int rown = wv * 32 + 16 + quad * 4 + r;
            int h = gh * 8 + (rown >> 4), w = gw * 16 + (rown & 15);
            size_t base = ((size_t)(b * 64 + h) * 64 + w) * 512 + nh * 32;
            oatt[base + l16]      = (__bf16)(o10[r] * rs1[r]);
            oatt[base + 16 + l16] = (__bf16)(o11[r] * rs1[r]);
        }
    }
}

extern "C" void kernel_launch(void* const* d_in, const int* in_sizes, int n_in,
                              void* d_out, int out_size, void* d_ws, size_t ws_size,
                              hipStream_t stream) {
    const float* x     = (const float*)d_in[0];
    const float* peq   = (const float*)d_in[1];
    const float* pekv  = (const float*)d_in[2];
    const float* mask  = (const float*)d_in[3];
    const float* wq    = (const float*)d_in[4];
    const float* bq    = (const float*)d_in[5];
    const float* wkv   = (const float*)d_in[6];
    const float* bkv   = (const float*)d_in[7];
    const float* wproj = (const float*)d_in[8];
    const float* bproj = (const float*)d_in[9];
    float* out = (float*)d_out;

    char* ws = (char*)d_ws;
    // workspace layout (bytes):
    //   [0, 33554432)            xb (bf16 32768x512)  -- reused as o_attn after GEMM1
    //   [33554432, 35127296)     wqkvT (bf16 1536x512) -- reused as mask flags after GEMM1
    //   [35127296, 35651584)     wpT   (bf16 512x512)
    //   [35651584, 136314880)    qkv   (bf16 [3][16][32768][32])
    __bf16* xb    = (__bf16*)(ws);
    __bf16* oatt  = (__bf16*)(ws);
    __bf16* wqkvT = (__bf16*)(ws + 33554432);
    int*    mflag = (int*)(ws + 33554432);
    __bf16* wpT   = (__bf16*)(ws + 35127296);
    __bf16* qkv   = (__bf16*)(ws + 35651584);

    cast_x_kernel<<<8192, 256, 0, stream>>>((const float4*)x, (bf16x8*)xb);
    transpose_cast_kernel<<<dim3(16, 16), dim3(32, 8), 0, stream>>>(wq, wqkvT, 512, 512);
    transpose_cast_kernel<<<dim3(32, 16), dim3(32, 8), 0, stream>>>(wkv, wqkvT + 512 * 512, 512, 1024);
    transpose_cast_kernel<<<dim3(16, 16), dim3(32, 8), 0, stream>>>(wproj, wpT, 512, 512);

    gemm256<<<dim3(128, 6), 512, 0, stream>>>(xb, wqkvT, bq, bkv, qkv, 1536, 0);
    mask_flag_kernel<<<32, 256, 0, stream>>>(mask, mflag);
    attn_kernel<<<4096, 256, 0, stream>>>(qkv, peq, pekv, mask, mflag, oatt);
    gemm256<<<dim3(128, 2), 512, 0, stream>>>(oatt, wpT, bproj, bproj, out, 512, 1);
}

// Round 4
// 321.236 us; speedup vs baseline: 1.0235x; 1.0235x over previous
//
#include <hip/hip_runtime.h>

typedef __bf16 bf16x8 __attribute__((ext_vector_type(8)));
typedef __bf16 bf16x4 __attribute__((ext_vector_type(4)));
typedef float f32x4 __attribute__((ext_vector_type(4)));

#define DEV __device__ __forceinline__

DEV f32x4 mfma16(bf16x8 a, bf16x8 b, f32x4 c) {
    return __builtin_amdgcn_mfma_f32_16x16x32_bf16(a, b, c, 0, 0, 0);
}

DEV void async16(const void* g, void* l) {
    __builtin_amdgcn_global_load_lds((__attribute__((address_space(1))) void*)g,
                                     (__attribute__((address_space(3))) void*)l, 16, 0, 0);
}

// compiler-only ordering fence (no instruction emitted)
#define LDS_FENCE() asm volatile("" ::: "memory")
// raw barrier / counted vmcnt (never drain to 0 inside the K-loop)
#define BARRIER() asm volatile("s_barrier" ::: "memory")
#define VMCNT(n) asm volatile("s_waitcnt vmcnt(" #n ")" ::: "memory")

// ---------------- cast x (f32 -> bf16), 8 elems/thread ----------------
__global__ __launch_bounds__(256) void cast_x_kernel(const float4* __restrict__ in,
                                                     bf16x8* __restrict__ out) {
    int i = blockIdx.x * 256 + threadIdx.x;
    float4 a = in[2 * i], b = in[2 * i + 1];
    bf16x8 o;
    o[0] = (__bf16)a.x; o[1] = (__bf16)a.y; o[2] = (__bf16)a.z; o[3] = (__bf16)a.w;
    o[4] = (__bf16)b.x; o[5] = (__bf16)b.y; o[6] = (__bf16)b.z; o[7] = (__bf16)b.w;
    out[i] = o;
}

// ------------- transpose + cast: src (R x C f32) -> dst (C x R bf16) -------------
__global__ void transpose_cast_kernel(const float* __restrict__ src,
                                      __bf16* __restrict__ dst, int R, int C) {
    __shared__ float tile[32][33];
    int tx = threadIdx.x, ty = threadIdx.y;
    int c0 = blockIdx.x * 32, r0 = blockIdx.y * 32;
#pragma unroll
    for (int j = 0; j < 4; ++j)
        tile[ty + j * 8][tx] = src[(size_t)(r0 + ty + j * 8) * C + c0 + tx];
    __syncthreads();
#pragma unroll
    for (int j = 0; j < 4; ++j)
        dst[(size_t)(c0 + ty + j * 8) * R + r0 + tx] = (__bf16)tile[tx][ty + j * 8];
}

// ---------------- mask nonzero flags: flags[g] = any(mask[g] != 0) ----------------
__global__ __launch_bounds__(256) void mask_flag_kernel(const float* __restrict__ mask,
                                                        int* __restrict__ flags) {
    int g = blockIdx.x;
    const float4* m4 = (const float4*)(mask + (size_t)g * 32768);
    int any = 0;
    for (int i = threadIdx.x; i < 8192; i += 256) {
        float4 v = m4[i];
        any |= (v.x != 0.f) | (v.y != 0.f) | (v.z != 0.f) | (v.w != 0.f);
    }
    any = __any(any) ? 1 : 0;
    __shared__ int s;
    if (threadIdx.x == 0) s = 0;
    __syncthreads();
    if ((threadIdx.x & 63) == 0 && any) atomicOr(&s, 1);
    __syncthreads();
    if (threadIdx.x == 0) flags[g] = s;
}

// stage one 16-KiB unit (matrix X, K-half of K-tile): 2 loads/thread.
// dest chunk d = i*512+tid (lane-linear, as global_load_lds requires);
// content at dest chunk d (r=d>>2, dc=d&3) is logical chunk cc = dc ^ ((r>>1)&3)
// -> pre-swizzled GLOBAL source, LDS stays linear. koff = kt*64 + h*32 (elems).
// Swizzle ((r>>1)&3) (NOT (r>>2)): with 64-B rows, bank-group(r,chunk) =
// (4r+chunk) mod 8; this choice makes every 8 consecutive lanes of a
// ds_read_b128 hit all 8 groups -> conflict-free (round-3's (r>>2) variant
// measured 4 extra cyc/read).
DEV void stage_unit(const __bf16* __restrict__ Gbase, __bf16* unit, int tid, int koff) {
#pragma unroll
    for (int i = 0; i < 2; ++i) {
        int d = i * 512 + tid;
        int r = d >> 2;
        int cc = (d & 3) ^ ((r >> 1) & 3);
        async16(Gbase + (size_t)r * 512 + koff + cc * 8, unit + d * 8);
    }
}

// ---------------- GEMM: C = A[M,512] * Bt[N,512]^T + bias ----------------
// 256x256 tile, BK=64, 8 waves (2M x 4N). Per-phase schedule (T3+T4+T5):
// LDS As/Bs[par][khalf][256x32] -- each (matrix, khalf) unit is a contiguous
// 16 KiB block. 4 phases per K-tile {(mh,ks)}:
// [ds_reads | stage 1 unit | barrier | 16 MFMA | vmcnt | barrier].
// The counted vmcnt covering phase p's units sits at the END of phase p-1,
// BEFORE its closing barrier (every wave's wait precedes the barrier the
// reader crosses). Steady state holds 8-12 loads in flight; tail 8 -> 4 -> 0.
//
// BLOCK MAPPING (L2 locality): 1-D grid, XCD-aware bm-major. xcd = id&7 owns
// a contiguous bm range; the nbn bn-siblings of each bm are ADJACENT slots ->
// run concurrently on the same XCD -> A panel crosses L3->L2 once and is
// read nbn times from L2 (grid-(128,nbn) put siblings 128 ids = one full
// machine-round apart -> 8MB/XCD concurrent working set -> L2 thrash -> all
// staging served from L3; that latency was the 24%-MfmaUtil plateau).
// mode 0: write bf16 qkv relayout [type][nh][32768][32]   (N=1536, nbn=6)
// mode 1: write f32 row-major C[M][N]                     (N=512,  nbn=2)
__global__ __launch_bounds__(512, 2) void gemm256(const __bf16* __restrict__ A,
                                                  const __bf16* __restrict__ Bt,
                                                  const float* __restrict__ bias0,
                                                  const float* __restrict__ bias1,
                                                  void* __restrict__ Cout, int N, int mode) {
    __shared__ __bf16 As[2][2][256 * 32];
    __shared__ __bf16 Bs[2][2][256 * 32];
    const int tid = threadIdx.x;
    const int nbn = N >> 8;                       // 256-col tiles
    const int per_xcd = gridDim.x >> 3;           // grid is 128*nbn, %8 == 0
    const int w = (blockIdx.x & 7) * per_xcd + (blockIdx.x >> 3);
    const int bm = w / nbn, bn = w % nbn;
    const int lane = tid & 63, wv = tid >> 6;
    const int quad = lane >> 4, l16 = lane & 15;
    const int wm = (wv >> 2) * 128, wn = (wv & 3) * 64;
    const __bf16* Abase = A + (size_t)bm * 256 * 512;
    const __bf16* Bbase = Bt + (size_t)bn * 256 * 512;

    f32x4 acc[8][4] = {};

    // prologue: units A(0,0),B(0,0),A(0,1),B(0,1),A(1,0),B(1,0)  (12 loads)
    stage_unit(Abase, &As[0][0][0], tid, 0 * 64 + 0);
    stage_unit(Bbase, &Bs[0][0][0], tid, 0 * 64 + 0);
    stage_unit(Abase, &As[0][1][0], tid, 0 * 64 + 32);
    stage_unit(Bbase, &Bs[0][1][0], tid, 0 * 64 + 32);
    stage_unit(Abase, &As[1][0][0], tid, 1 * 64 + 0);
    stage_unit(Bbase, &Bs[1][0][0], tid, 1 * 64 + 0);
    VMCNT(8);   // A(0,0), B(0,0) landed
    BARRIER();

#pragma unroll
    for (int kt = 0; kt < 8; ++kt) {
        const int par = kt & 1;
        bf16x8 bfm[4];
#pragma unroll
        for (int ph = 0; ph < 4; ++ph) {
            const int mh = ph & 1, ks = ph >> 1;
            // ds-load register subtiles (4 A-frags; +4 B-frags at ks start)
            bf16x8 af[4];
            if (mh == 0) {
#pragma unroll
                for (int t = 0; t < 4; ++t) {
                    int rb = wn + t * 16 + l16;
                    bfm[t] = *(const bf16x8*)&Bs[par][ks][rb * 32 + ((quad ^ ((rb >> 1) & 3)) << 3)];
                }
            }
#pragma unroll
            for (int t = 0; t < 4; ++t) {
                int ra = wm + mh * 64 + t * 16 + l16;
                af[t] = *(const bf16x8*)&As[par][ks][ra * 32 + ((quad ^ ((ra >> 1) & 3)) << 3)];
            }
            // stage exactly one unit per phase (slot's last reader finished a
            // full barrier-pair earlier -- overwrite safe)
            if (ph == 0 && kt + 1 < 8) stage_unit(Abase, &As[par ^ 1][1][0], tid, (kt + 1) * 64 + 32);
            if (ph == 1 && kt + 1 < 8) stage_unit(Bbase, &Bs[par ^ 1][1][0], tid, (kt + 1) * 64 + 32);
            if (ph == 2 && kt + 2 < 8) stage_unit(Abase, &As[par][0][0], tid, (kt + 2) * 64 + 0);
            if (ph == 3 && kt + 2 < 8) stage_unit(Bbase, &Bs[par][0][0], tid, (kt + 2) * 64 + 0);
            BARRIER();
            __builtin_amdgcn_s_setprio(1);
#pragma unroll
            for (int mt = 0; mt < 4; ++mt)
#pragma unroll
                for (int nt = 0; nt < 4; ++nt)
                    acc[mh * 4 + mt][nt] = mfma16(af[mt], bfm[nt], acc[mh * 4 + mt][nt]);
            __builtin_amdgcn_s_setprio(0);
            // counted wait for the NEXT phase's units, before the barrier the
            // next phase's readers will cross:
            //   end ph1: A(kt,1),B(kt,1)   end ph3: A(kt+1,0),B(kt+1,0)
            if (ph == 1) { if (kt < 7) { VMCNT(8); } else { VMCNT(0); } }
            if (ph == 3) { if (kt < 6) { VMCNT(8); } else if (kt == 6) { VMCNT(4); } }
            BARRIER();
        }
    }

    // acc[a] covers rows (a>>2)*64 + (a&3)*16 of the wave's 128-row strip
#pragma unroll
    for (int nt = 0; nt < 4; ++nt) {
        int ng = bn * 256 + wn + nt * 16 + l16;
        float bias = (ng < 512) ? bias0[ng] : bias1[ng - 512];
        if (mode == 0) {
            int type = ng >> 9, nhh = (ng >> 5) & 15, ch = ng & 31;
            __bf16* dst = (__bf16*)Cout + (size_t)type * 16777216 + (size_t)nhh * 1048576 + ch;
#pragma unroll
            for (int mt = 0; mt < 8; ++mt)
#pragma unroll
                for (int r = 0; r < 4; ++r) {
                    int mg = bm * 256 + wm + (mt >> 2) * 64 + (mt & 3) * 16 + quad * 4 + r;
                    dst[(size_t)mg * 32] = (__bf16)(acc[mt][nt][r] + bias);
                }
        } else {
#pragma unroll
            for (int mt = 0; mt < 8; ++mt)
#pragma unroll
                for (int r = 0; r < 4; ++r) {
                    int mg = bm * 256 + wm + (mt >> 2) * 64 + (mt & 3) * 16 + quad * 4 + r;
                    ((float*)Cout)[(size_t)mg * N + ng] = acc[mt][nt][r] + bias;
                }
        }
    }
}

// ---------------- fused window attention, one workgroup per (b, g, nh) ----------------
// qkv layout: [type(q/k/v)][nh][row = (b*64+h)*64+w][32 ch]  (bf16)
// N=128 queries, 2N=256 keys (key = roll*128 + ws1*16 + ws2)
#define ATT_SCALE 0.17677669529663687f

__global__ __launch_bounds__(256, 4) void attn_kernel(const __bf16* __restrict__ qkv,
                                                      const float* __restrict__ peq,
                                                      const float* __restrict__ pekv,
                                                      const float* __restrict__ mask,
                                                      const int* __restrict__ mflags,
                                                      __bf16* __restrict__ oatt) {
    // LDS 38400 B -> 4 blocks/CU:
    //   [0,16384)      Ks: swizzled [256 keys][32 ch], chunk p = c ^ ((key>>1)&3)
    //   [16384,33280)  Vt[32][264]
    //   [33280,38400)  Ps: 4 per-wave slices of [16 rows][40]
    __shared__ __align__(16) char smem[38400];
    __bf16* Ks = (__bf16*)smem;
    __bf16* Vt = (__bf16*)(smem + 16384);
    __bf16* Ps = (__bf16*)(smem + 33280);

    const int tid = threadIdx.x;
    // XCD swizzle: 16 nh-siblings (same qkv rows) -> same XCD; XCD x <- batch x
    const int bid = ((blockIdx.x & 7) << 9) | (blockIdx.x >> 3);
    const int b = bid >> 9;
    const int g = (bid >> 4) & 31;
    const int nh = bid & 15;
    const int gh = g >> 2, gw = g & 3;
    const int lane = tid & 63, wv = tid >> 6;
    const int quad = lane >> 4, l16 = lane & 15;

    const __bf16* qq = qkv + (size_t)nh * 1048576;
    const __bf16* kkp = qkv + 16777216 + (size_t)nh * 1048576;
    const __bf16* vvp = qkv + 33554432 + (size_t)nh * 1048576;

    // ---- stage K with rotary + roll into swizzled layout ----
#pragma unroll
    for (int it = 0; it < 4; ++it) {
        int item = it * 256 + tid;
        int ko = item >> 2, c8 = item & 3;
        int roll = ko >> 7, n = ko & 127;
        int h = (gh * 8 + (n >> 4) + (roll ? 60 : 4)) & 63;  // roll0:+4, roll1:-4 (mod 64)
        int w = gw * 16 + (n & 15);
        int row = (b * 64 + h) * 64 + w;
        bf16x8 v = *(const bf16x8*)(kkp + (size_t)row * 32 + c8 * 8);
        int pidx = (g * 256 + ko) * 16 + c8 * 4;
        float4 c4 = *(const float4*)(pekv + pidx);
        float4 s4 = *(const float4*)(pekv + 131072 + pidx);
        float cs[4] = {c4.x, c4.y, c4.z, c4.w}, sn[4] = {s4.x, s4.y, s4.z, s4.w};
        bf16x4 lo, hi;
#pragma unroll
        for (int j = 0; j < 4; ++j) {
            float k0 = (float)v[2 * j], k1 = (float)v[2 * j + 1];
            lo[j] = (__bf16)(k0 * cs[j] - k1 * sn[j]);
            hi[j] = (__bf16)(k1 * cs[j] + k0 * sn[j]);
        }
        int sw = (ko >> 1) & 3;
        int base = ko * 32, off = (c8 & 1) * 4;
        *(bf16x4*)&Ks[base + (((c8 >> 1) ^ sw) << 3) + off]       = lo;
        *(bf16x4*)&Ks[base + (((2 + (c8 >> 1)) ^ sw) << 3) + off] = hi;
    }
    // ---- stage V transposed (Vt[ch][key]) ----
#pragma unroll
    for (int it = 0; it < 4; ++it) {
        int ko = tid;
        int roll = ko >> 7, n = ko & 127;
        int h = (gh * 8 + (n >> 4) + (roll ? 60 : 4)) & 63;
        int w = gw * 16 + (n & 15);
        int row = (b * 64 + h) * 64 + w;
        bf16x8 v = *(const bf16x8*)(vvp + (size_t)row * 32 + it * 8);
#pragma unroll
        for (int j = 0; j < 8; ++j)
            Vt[(it * 8 + j) * 264 + ko] = v[j];
    }

    // ---- Q A-fragments straight into registers (overlaps staging latency) ----
    bf16x8 aq[2];
    {
        const int halfsel = quad & 1;      // raw channel half
        const bool hi_half = quad >= 2;    // rotary output half
#pragma unroll
        for (int rt = 0; rt < 2; ++rt) {
            int n = wv * 32 + rt * 16 + l16;
            int h = gh * 8 + (n >> 4), w = gw * 16 + (n & 15);
            int row = (b * 64 + h) * 64 + w;
            const __bf16* qp = qq + (size_t)row * 32 + halfsel * 16;
            bf16x8 rA = *(const bf16x8*)qp;
            bf16x8 rB = *(const bf16x8*)(qp + 8);
            int pb = (g * 128 + n) * 16 + halfsel * 8;
            float4 ca = *(const float4*)(peq + pb);
            float4 cb = *(const float4*)(peq + pb + 4);
            float4 sa = *(const float4*)(peq + 65536 + pb);
            float4 sb = *(const float4*)(peq + 65536 + pb + 4);
            float cc[8] = {ca.x, ca.y, ca.z, ca.w, cb.x, cb.y, cb.z, cb.w};
            float ss[8] = {sa.x, sa.y, sa.z, sa.w, sb.x, sb.y, sb.z, sb.w};
#pragma unroll
            for (int j = 0; j < 8; ++j) {
                float q0 = (float)(j < 4 ? rA[2 * j] : rB[2 * (j - 4)]);
                float q1 = (float)(j < 4 ? rA[2 * j + 1] : rB[2 * (j - 4) + 1]);
                float r = hi_half ? (q1 * cc[j] + q0 * ss[j]) : (q0 * cc[j] - q1 * ss[j]);
                aq[rt][j] = (__bf16)(r * ATT_SCALE);
            }
        }
    }
    __syncthreads();  // the ONLY barrier

    // ---- barrier-free flash loop: 8 chunks x 32 keys ----
    f32x4 o00 = {}, o01 = {}, o10 = {}, o11 = {};
    f32x4 rs0 = {}, rs1 = {};
    const bool use_mask = mflags[g] != 0;
    const float* mg = mask + (size_t)g * 32768;
    __bf16* Pw = Ps + wv * 640;           // private [16][40] slice
    const int arow = l16 * 40 + quad * 8; // A-frag read address (elems)

#pragma unroll 2
    for (int ch = 0; ch < 8; ++ch) {
        bf16x8 vb0 = *(const bf16x8*)&Vt[l16 * 264 + ch * 32 + quad * 8];
        bf16x8 vb1 = *(const bf16x8*)&Vt[(16 + l16) * 264 + ch * 32 + quad * 8];
        f32x4 z = {0.f, 0.f, 0.f, 0.f};
        int key0 = ch * 32 + l16, key1 = key0 + 16;
        bf16x8 bk0 = *(const bf16x8*)&Ks[key0 * 32 + ((quad ^ ((key0 >> 1) & 3)) << 3)];
        bf16x8 bk1 = *(const bf16x8*)&Ks[key1 * 32 + ((quad ^ ((key1 >> 1) & 3)) << 3)];
        f32x4 s00 = mfma16(aq[0], bk0, z), s01 = mfma16(aq[0], bk1, z);
        f32x4 s10 = mfma16(aq[1], bk0, z), s11 = mfma16(aq[1], bk1, z);

        if (use_mask) {
#pragma unroll
            for (int r = 0; r < 4; ++r) {
                int r0 = (wv * 32 + quad * 4 + r) * 256 + ch * 32 + l16;
                int r1 = (wv * 32 + 16 + quad * 4 + r) * 256 + ch * 32 + l16;
                s00[r] += mg[r0];      s01[r] += mg[r0 + 16];
                s10[r] += mg[r1];      s11[r] += mg[r1 + 16];
            }
        }
#pragma unroll
        for (int r = 0; r < 4; ++r) {
            s00[r] = __expf(s00[r]); s01[r] = __expf(s01[r]);
            s10[r] = __expf(s10[r]); s11[r] = __expf(s11[r]);
            rs0[r] += s00[r] + s01[r];
            rs1[r] += s10[r] + s11[r];
        }
        // P(rt0) -> own slice -> A-frag; in-order per-wave DS pipe makes this safe
#pragma unroll
        for (int r = 0; r < 4; ++r) {
            Pw[(quad * 4 + r) * 40 + l16]      = (__bf16)s00[r];
            Pw[(quad * 4 + r) * 40 + 16 + l16] = (__bf16)s01[r];
        }
        LDS_FENCE();
        bf16x8 a0 = *(const bf16x8*)&Pw[arow];
        LDS_FENCE();
#pragma unroll
        for (int r = 0; r < 4; ++r) {
            Pw[(quad * 4 + r) * 40 + l16]      = (__bf16)s10[r];
            Pw[(quad * 4 + r) * 40 + 16 + l16] = (__bf16)s11[r];
        }
        LDS_FENCE();
        bf16x8 a1 = *(const bf16x8*)&Pw[arow];
        LDS_FENCE();
        o00 = mfma16(a0, vb0, o00); o01 = mfma16(a0, vb1, o01);
        o10 = mfma16(a1, vb0, o10); o11 = mfma16(a1, vb1, o11);
    }

    // ---- finish row sums (16-lane butterfly) and normalize ----
#pragma unroll
    for (int off = 1; off < 16; off <<= 1) {
#pragma unroll
        for (int r = 0; r < 4; ++r) {
            rs0[r] += __shfl_xor(rs0[r], off);
            rs1[r] += __shfl_xor(rs1[r], off);
        }
    }
#pragma unroll
    for (int r = 0; r < 4; ++r) { rs0[r] = 1.f / rs0[r]; rs1[r] = 1.f / rs1[r]; }

    // ---- write O straight into (b,h,w, nh*32+c) layout (bf16) ----
#pragma unroll
    for (int r = 0; r < 4; ++r) {
        {
            int rown = wv * 32 + quad * 4 + r;
            int h = gh * 8 + (rown >> 4), w = gw * 16 + (rown & 15);
            size_t base = ((size_t)(b * 64 + h) * 64 + w) * 512 + nh * 32;
            oatt[base + l16]      = (__bf16)(o00[r] * rs0[r]);
            oatt[base + 16 + l16] = (__bf16)(o01[r] * rs0[r]);
        }
        {
            int rown = wv * 32 + 16 + quad * 4 + r;
            int h = gh * 8 + (rown >> 4), w = gw * 16 + (rown & 15);
            size_t base = ((size_t)(b * 64 + h) * 64 + w) * 512 + nh * 32;
            oatt[base + l16]      = (__bf16)(o10[r] * rs1[r]);
            oatt[base + 16 + l16] = (__bf16)(o11[r] * rs1[r]);
        }
    }
}

extern "C" void kernel_launch(void* const* d_in, const int* in_sizes, int n_in,
                              void* d_out, int out_size, void* d_ws, size_t ws_size,
                              hipStream_t stream) {
    const float* x     = (const float*)d_in[0];
    const float* peq   = (const float*)d_in[1];
    const float* pekv  = (const float*)d_in[2];
    const float* mask  = (const float*)d_in[3];
    const float* wq    = (const float*)d_in[4];
    const float* bq    = (const float*)d_in[5];
    const float* wkv   = (const float*)d_in[6];
    const float* bkv   = (const float*)d_in[7];
    const float* wproj = (const float*)d_in[8];
    const float* bproj = (const float*)d_in[9];
    float* out = (float*)d_out;

    char* ws = (char*)d_ws;
    // workspace layout (bytes):
    //   [0, 33554432)            xb (bf16 32768x512)  -- reused as o_attn after GEMM1
    //   [33554432, 35127296)     wqkvT (bf16 1536x512) -- reused as mask flags after GEMM1
    //   [35127296, 35651584)     wpT   (bf16 512x512)
    //   [35651584, 136314880)    qkv   (bf16 [3][16][32768][32])
    __bf16* xb    = (__bf16*)(ws);
    __bf16* oatt  = (__bf16*)(ws);
    __bf16* wqkvT = (__bf16*)(ws + 33554432);
    int*    mflag = (int*)(ws + 33554432);
    __bf16* wpT   = (__bf16*)(ws + 35127296);
    __bf16* qkv   = (__bf16*)(ws + 35651584);

    cast_x_kernel<<<8192, 256, 0, stream>>>((const float4*)x, (bf16x8*)xb);
    transpose_cast_kernel<<<dim3(16, 16), dim3(32, 8), 0, stream>>>(wq, wqkvT, 512, 512);
    transpose_cast_kernel<<<dim3(32, 16), dim3(32, 8), 0, stream>>>(wkv, wqkvT + 512 * 512, 512, 1024);
    transpose_cast_kernel<<<dim3(16, 16), dim3(32, 8), 0, stream>>>(wproj, wpT, 512, 512);

    gemm256<<<768, 512, 0, stream>>>(xb, wqkvT, bq, bkv, qkv, 1536, 0);
    mask_flag_kernel<<<32, 256, 0, stream>>>(mask, mflag);
    attn_kernel<<<4096, 256, 0, stream>>>(qkv, peq, pekv, mask, mflag, oatt);
    gemm256<<<256, 512, 0, stream>>>(oatt, wpT, bproj, bproj, out, 512, 1);
}

// Round 5
// 295.556 us; speedup vs baseline: 1.1124x; 1.0869x over previous
//
#include <hip/hip_runtime.h>

typedef __bf16 bf16x8 __attribute__((ext_vector_type(8)));
typedef __bf16 bf16x4 __attribute__((ext_vector_type(4)));
typedef float f32x4 __attribute__((ext_vector_type(4)));

#define DEV __device__ __forceinline__

DEV f32x4 mfma16(bf16x8 a, bf16x8 b, f32x4 c) {
    return __builtin_amdgcn_mfma_f32_16x16x32_bf16(a, b, c, 0, 0, 0);
}

DEV void async16(const void* g, void* l) {
    __builtin_amdgcn_global_load_lds((__attribute__((address_space(1))) void*)g,
                                     (__attribute__((address_space(3))) void*)l, 16, 0, 0);
}

// compiler-only ordering fence (no instruction emitted)
#define LDS_FENCE() asm volatile("" ::: "memory")
// raw barrier / counted vmcnt (never drain to 0 inside the K-loop)
#define BARRIER() asm volatile("s_barrier" ::: "memory")
#define VMCNT(n) asm volatile("s_waitcnt vmcnt(" #n ")" ::: "memory")

// ---------------- cast x (f32 -> bf16), 8 elems/thread ----------------
__global__ __launch_bounds__(256) void cast_x_kernel(const float4* __restrict__ in,
                                                     bf16x8* __restrict__ out) {
    int i = blockIdx.x * 256 + threadIdx.x;
    float4 a = in[2 * i], b = in[2 * i + 1];
    bf16x8 o;
    o[0] = (__bf16)a.x; o[1] = (__bf16)a.y; o[2] = (__bf16)a.z; o[3] = (__bf16)a.w;
    o[4] = (__bf16)b.x; o[5] = (__bf16)b.y; o[6] = (__bf16)b.z; o[7] = (__bf16)b.w;
    out[i] = o;
}

// ------------- transpose + cast: src (R x C f32) -> dst (C x R bf16) -------------
__global__ void transpose_cast_kernel(const float* __restrict__ src,
                                      __bf16* __restrict__ dst, int R, int C) {
    __shared__ float tile[32][33];
    int tx = threadIdx.x, ty = threadIdx.y;
    int c0 = blockIdx.x * 32, r0 = blockIdx.y * 32;
#pragma unroll
    for (int j = 0; j < 4; ++j)
        tile[ty + j * 8][tx] = src[(size_t)(r0 + ty + j * 8) * C + c0 + tx];
    __syncthreads();
#pragma unroll
    for (int j = 0; j < 4; ++j)
        dst[(size_t)(c0 + ty + j * 8) * R + r0 + tx] = (__bf16)tile[tx][ty + j * 8];
}

// ---------------- mask nonzero flags: flags[g] = any(mask[g] != 0) ----------------
__global__ __launch_bounds__(256) void mask_flag_kernel(const float* __restrict__ mask,
                                                        int* __restrict__ flags) {
    int g = blockIdx.x;
    const float4* m4 = (const float4*)(mask + (size_t)g * 32768);
    int any = 0;
    for (int i = threadIdx.x; i < 8192; i += 256) {
        float4 v = m4[i];
        any |= (v.x != 0.f) | (v.y != 0.f) | (v.z != 0.f) | (v.w != 0.f);
    }
    any = __any(any) ? 1 : 0;
    __shared__ int s;
    if (threadIdx.x == 0) s = 0;
    __syncthreads();
    if ((threadIdx.x & 63) == 0 && any) atomicOr(&s, 1);
    __syncthreads();
    if (threadIdx.x == 0) flags[g] = s;
}

// ---------------- GEMM: C = A[M,512] * Bt[N,512]^T + bias ----------------
// 128x128 tile, BK=64, 4 waves (2x2), 256 threads. DOUBLE-buffered 64 KiB LDS
// -> 2 INDEPENDENT blocks/CU: their vmcnt/barrier/prologue/epilogue stalls
// mutually overlap (m114 engine) -- the 1-WG/CU 256^2 pipelined structure was
// pinned at ~620 TF across 3 schedule variants because every stall was dead
// time. Counted vmcnt(8): stage tile kr+1 into buf^1, wait for exactly the
// 8 oldest loads (= tile kr), never drain mid-loop. LDS tiles XOR-swizzled
// chunk p = c ^ (r & 7) within 128-B rows, applied on the GLOBAL source
// address (global_load_lds dest stays lane-linear); read sweep covers all 8
// bank-groups per 16 lanes -> conflict-free (round-0/round-4 measured 0).
// Block mapping: 1-D grid, XCD-aware bm-major (bijective, grid % 8 == 0);
// bn-siblings of one bm sit on adjacent slots of the same XCD -> A panel
// crosses L3->L2 once (round-4 verified: FETCH == one A read).
// mode 0: write bf16 qkv relayout [type][nh][32768][32]   (N=1536)
// mode 1: write f32 row-major C[M][N]
__global__ __launch_bounds__(256, 2) void gemm128(const __bf16* __restrict__ A,
                                                  const __bf16* __restrict__ Bt,
                                                  const float* __restrict__ bias0,
                                                  const float* __restrict__ bias1,
                                                  void* __restrict__ Cout, int N, int mode) {
    __shared__ __bf16 As[2][128 * 64];
    __shared__ __bf16 Bs[2][128 * 64];
    const int tid = threadIdx.x;
    const int nbn = N >> 7;                  // 128-col tiles
    const int per_xcd = gridDim.x >> 3;      // grid % 8 == 0
    const int w = (blockIdx.x & 7) * per_xcd + (blockIdx.x >> 3);
    const int bm = w / nbn, bn = w % nbn;
    const int lane = tid & 63, wv = tid >> 6;
    const int quad = lane >> 4, l16 = lane & 15;
    const int wm = (wv & 1) * 64, wn = (wv >> 1) * 64;
    const __bf16* Abase = A + (size_t)bm * 128 * 512;
    const __bf16* Bbase = Bt + (size_t)bn * 128 * 512;
    f32x4 acc[4][4] = {};

    // staging geometry: 4 chunks of 16B per matrix per K-tile; dest chunk
    // d = i*256+tid (lane-linear), content = logical chunk (d&7) ^ (row&7)
    int s_off[4];
#pragma unroll
    for (int i = 0; i < 4; ++i) {
        int chunk = i * 256 + tid;
        int r = chunk >> 3, cc = chunk & 7;
        s_off[i] = r * 512 + ((cc ^ (r & 7)) << 3);
    }

    // prologue: tile 0 into buffer 0 (8 loads/thread)
#pragma unroll
    for (int i = 0; i < 4; ++i) {
        int chunk = i * 256 + tid;
        async16(Abase + s_off[i], &As[0][chunk * 8]);
        async16(Bbase + s_off[i], &Bs[0][chunk * 8]);
    }

#pragma unroll
    for (int kr = 0; kr < 8; ++kr) {
        const int c = kr & 1;
        if (kr < 7) {
            // issue tile kr+1 into the other buffer (its previous readers
            // finished before the end-barrier of iter kr-1, already crossed)
#pragma unroll
            for (int i = 0; i < 4; ++i) {
                int chunk = i * 256 + tid;
                async16(Abase + s_off[i] + (kr + 1) * 64, &As[c ^ 1][chunk * 8]);
                async16(Bbase + s_off[i] + (kr + 1) * 64, &Bs[c ^ 1][chunk * 8]);
            }
            VMCNT(8);   // 8 oldest = tile kr landed; kr+1's 8 stay in flight
        } else {
            VMCNT(0);   // last tile
        }
        BARRIER();      // all waves' tile-kr loads landed before any read
#pragma unroll
        for (int kk = 0; kk < 2; ++kk) {
            bf16x8 af[4], bfm[4];
#pragma unroll
            for (int t = 0; t < 4; ++t) {
                int ra = wm + t * 16 + l16, rb = wn + t * 16 + l16;
                int cch = kk * 4 + quad;
                af[t]  = *(const bf16x8*)&As[c][ra * 64 + ((cch ^ (ra & 7)) << 3)];
                bfm[t] = *(const bf16x8*)&Bs[c][rb * 64 + ((cch ^ (rb & 7)) << 3)];
            }
            __builtin_amdgcn_s_setprio(1);
#pragma unroll
            for (int mt = 0; mt < 4; ++mt)
#pragma unroll
                for (int nt = 0; nt < 4; ++nt)
                    acc[mt][nt] = mfma16(af[mt], bfm[nt], acc[mt][nt]);
            __builtin_amdgcn_s_setprio(0);
        }
        BARRIER();      // all reads of buf[c] done -> next iter may overwrite
    }

#pragma unroll
    for (int nt = 0; nt < 4; ++nt) {
        int ng = bn * 128 + wn + nt * 16 + l16;
        float bias = (ng < 512) ? bias0[ng] : bias1[ng - 512];
        if (mode == 0) {
            int type = ng >> 9, nhh = (ng >> 5) & 15, ch = ng & 31;
            __bf16* dst = (__bf16*)Cout + (size_t)type * 16777216 + (size_t)nhh * 1048576 + ch;
#pragma unroll
            for (int mt = 0; mt < 4; ++mt)
#pragma unroll
                for (int r = 0; r < 4; ++r) {
                    int mg = bm * 128 + wm + mt * 16 + quad * 4 + r;
                    dst[(size_t)mg * 32] = (__bf16)(acc[mt][nt][r] + bias);
                }
        } else {
#pragma unroll
            for (int mt = 0; mt < 4; ++mt)
#pragma unroll
                for (int r = 0; r < 4; ++r) {
                    int mg = bm * 128 + wm + mt * 16 + quad * 4 + r;
                    ((float*)Cout)[(size_t)mg * N + ng] = acc[mt][nt][r] + bias;
                }
        }
    }
}

// ---------------- fused window attention, one workgroup per (b, g, nh) ----------------
// qkv layout: [type(q/k/v)][nh][row = (b*64+h)*64+w][32 ch]  (bf16)
// N=128 queries, 2N=256 keys (key = roll*128 + ws1*16 + ws2)
#define ATT_SCALE 0.17677669529663687f

__global__ __launch_bounds__(256, 4) void attn_kernel(const __bf16* __restrict__ qkv,
                                                      const float* __restrict__ peq,
                                                      const float* __restrict__ pekv,
                                                      const float* __restrict__ mask,
                                                      const int* __restrict__ mflags,
                                                      __bf16* __restrict__ oatt) {
    // LDS 38400 B -> 4 blocks/CU:
    //   [0,16384)      Ks: swizzled [256 keys][32 ch], chunk p = c ^ ((key>>1)&3)
    //   [16384,33280)  Vt[32][264]
    //   [33280,38400)  Ps: 4 per-wave slices of [16 rows][40]
    __shared__ __align__(16) char smem[38400];
    __bf16* Ks = (__bf16*)smem;
    __bf16* Vt = (__bf16*)(smem + 16384);
    __bf16* Ps = (__bf16*)(smem + 33280);

    const int tid = threadIdx.x;
    // XCD swizzle: 16 nh-siblings (same qkv rows) -> same XCD; XCD x <- batch x
    const int bid = ((blockIdx.x & 7) << 9) | (blockIdx.x >> 3);
    const int b = bid >> 9;
    const int g = (bid >> 4) & 31;
    const int nh = bid & 15;
    const int gh = g >> 2, gw = g & 3;
    const int lane = tid & 63, wv = tid >> 6;
    const int quad = lane >> 4, l16 = lane & 15;

    const __bf16* qq = qkv + (size_t)nh * 1048576;
    const __bf16* kkp = qkv + 16777216 + (size_t)nh * 1048576;
    const __bf16* vvp = qkv + 33554432 + (size_t)nh * 1048576;

    // ---- stage K with rotary + roll into swizzled layout ----
#pragma unroll
    for (int it = 0; it < 4; ++it) {
        int item = it * 256 + tid;
        int ko = item >> 2, c8 = item & 3;
        int roll = ko >> 7, n = ko & 127;
        int h = (gh * 8 + (n >> 4) + (roll ? 60 : 4)) & 63;  // roll0:+4, roll1:-4 (mod 64)
        int w = gw * 16 + (n & 15);
        int row = (b * 64 + h) * 64 + w;
        bf16x8 v = *(const bf16x8*)(kkp + (size_t)row * 32 + c8 * 8);
        int pidx = (g * 256 + ko) * 16 + c8 * 4;
        float4 c4 = *(const float4*)(pekv + pidx);
        float4 s4 = *(const float4*)(pekv + 131072 + pidx);
        float cs[4] = {c4.x, c4.y, c4.z, c4.w}, sn[4] = {s4.x, s4.y, s4.z, s4.w};
        bf16x4 lo, hi;
#pragma unroll
        for (int j = 0; j < 4; ++j) {
            float k0 = (float)v[2 * j], k1 = (float)v[2 * j + 1];
            lo[j] = (__bf16)(k0 * cs[j] - k1 * sn[j]);
            hi[j] = (__bf16)(k1 * cs[j] + k0 * sn[j]);
        }
        int sw = (ko >> 1) & 3;
        int base = ko * 32, off = (c8 & 1) * 4;
        *(bf16x4*)&Ks[base + (((c8 >> 1) ^ sw) << 3) + off]       = lo;
        *(bf16x4*)&Ks[base + (((2 + (c8 >> 1)) ^ sw) << 3) + off] = hi;
    }
    // ---- stage V transposed (Vt[ch][key]) ----
#pragma unroll
    for (int it = 0; it < 4; ++it) {
        int ko = tid;
        int roll = ko >> 7, n = ko & 127;
        int h = (gh * 8 + (n >> 4) + (roll ? 60 : 4)) & 63;
        int w = gw * 16 + (n & 15);
        int row = (b * 64 + h) * 64 + w;
        bf16x8 v = *(const bf16x8*)(vvp + (size_t)row * 32 + it * 8);
#pragma unroll
        for (int j = 0; j < 8; ++j)
            Vt[(it * 8 + j) * 264 + ko] = v[j];
    }

    // ---- Q A-fragments straight into registers (overlaps staging latency) ----
    bf16x8 aq[2];
    {
        const int halfsel = quad & 1;      // raw channel half
        const bool hi_half = quad >= 2;    // rotary output half
#pragma unroll
        for (int rt = 0; rt < 2; ++rt) {
            int n = wv * 32 + rt * 16 + l16;
            int h = gh * 8 + (n >> 4), w = gw * 16 + (n & 15);
            int row = (b * 64 + h) * 64 + w;
            const __bf16* qp = qq + (size_t)row * 32 + halfsel * 16;
            bf16x8 rA = *(const bf16x8*)qp;
            bf16x8 rB = *(const bf16x8*)(qp + 8);
            int pb = (g * 128 + n) * 16 + halfsel * 8;
            float4 ca = *(const float4*)(peq + pb);
            float4 cb = *(const float4*)(peq + pb + 4);
            float4 sa = *(const float4*)(peq + 65536 + pb);
            float4 sb = *(const float4*)(peq + 65536 + pb + 4);
            float cc[8] = {ca.x, ca.y, ca.z, ca.w, cb.x, cb.y, cb.z, cb.w};
            float ss[8] = {sa.x, sa.y, sa.z, sa.w, sb.x, sb.y, sb.z, sb.w};
#pragma unroll
            for (int j = 0; j < 8; ++j) {
                float q0 = (float)(j < 4 ? rA[2 * j] : rB[2 * (j - 4)]);
                float q1 = (float)(j < 4 ? rA[2 * j + 1] : rB[2 * (j - 4) + 1]);
                float r = hi_half ? (q1 * cc[j] + q0 * ss[j]) : (q0 * cc[j] - q1 * ss[j]);
                aq[rt][j] = (__bf16)(r * ATT_SCALE);
            }
        }
    }
    __syncthreads();  // the ONLY barrier

    // ---- barrier-free flash loop: 8 chunks x 32 keys ----
    f32x4 o00 = {}, o01 = {}, o10 = {}, o11 = {};
    f32x4 rs0 = {}, rs1 = {};
    const bool use_mask = mflags[g] != 0;
    const float* mg = mask + (size_t)g * 32768;
    __bf16* Pw = Ps + wv * 640;           // private [16][40] slice
    const int arow = l16 * 40 + quad * 8; // A-frag read address (elems)

#pragma unroll 2
    for (int ch = 0; ch < 8; ++ch) {
        bf16x8 vb0 = *(const bf16x8*)&Vt[l16 * 264 + ch * 32 + quad * 8];
        bf16x8 vb1 = *(const bf16x8*)&Vt[(16 + l16) * 264 + ch * 32 + quad * 8];
        f32x4 z = {0.f, 0.f, 0.f, 0.f};
        int key0 = ch * 32 + l16, key1 = key0 + 16;
        bf16x8 bk0 = *(const bf16x8*)&Ks[key0 * 32 + ((quad ^ ((key0 >> 1) & 3)) << 3)];
        bf16x8 bk1 = *(const bf16x8*)&Ks[key1 * 32 + ((quad ^ ((key1 >> 1) & 3)) << 3)];
        f32x4 s00 = mfma16(aq[0], bk0, z), s01 = mfma16(aq[0], bk1, z);
        f32x4 s10 = mfma16(aq[1], bk0, z), s11 = mfma16(aq[1], bk1, z);

        if (use_mask) {
#pragma unroll
            for (int r = 0; r < 4; ++r) {
                int r0 = (wv * 32 + quad * 4 + r) * 256 + ch * 32 + l16;
                int r1 = (wv * 32 + 16 + quad * 4 + r) * 256 + ch * 32 + l16;
                s00[r] += mg[r0];      s01[r] += mg[r0 + 16];
                s10[r] += mg[r1];      s11[r] += mg[r1 + 16];
            }
        }
#pragma unroll
        for (int r = 0; r < 4; ++r) {
            s00[r] = __expf(s00[r]); s01[r] = __expf(s01[r]);
            s10[r] = __expf(s10[r]); s11[r] = __expf(s11[r]);
            rs0[r] += s00[r] + s01[r];
            rs1[r] += s10[r] + s11[r];
        }
        // P(rt0) -> own slice -> A-frag; in-order per-wave DS pipe makes this safe
#pragma unroll
        for (int r = 0; r < 4; ++r) {
            Pw[(quad * 4 + r) * 40 + l16]      = (__bf16)s00[r];
            Pw[(quad * 4 + r) * 40 + 16 + l16] = (__bf16)s01[r];
        }
        LDS_FENCE();
        bf16x8 a0 = *(const bf16x8*)&Pw[arow];
        LDS_FENCE();
#pragma unroll
        for (int r = 0; r < 4; ++r) {
            Pw[(quad * 4 + r) * 40 + l16]      = (__bf16)s10[r];
            Pw[(quad * 4 + r) * 40 + 16 + l16] = (__bf16)s11[r];
        }
        LDS_FENCE();
        bf16x8 a1 = *(const bf16x8*)&Pw[arow];
        LDS_FENCE();
        o00 = mfma16(a0, vb0, o00); o01 = mfma16(a0, vb1, o01);
        o10 = mfma16(a1, vb0, o10); o11 = mfma16(a1, vb1, o11);
    }

    // ---- finish row sums (16-lane butterfly) and normalize ----
#pragma unroll
    for (int off = 1; off < 16; off <<= 1) {
#pragma unroll
        for (int r = 0; r < 4; ++r) {
            rs0[r] += __shfl_xor(rs0[r], off);
            rs1[r] += __shfl_xor(rs1[r], off);
        }
    }
#pragma unroll
    for (int r = 0; r < 4; ++r) { rs0[r] = 1.f / rs0[r]; rs1[r] = 1.f / rs1[r]; }

    // ---- write O straight into (b,h,w, nh*32+c) layout (bf16) ----
#pragma unroll
    for (int r = 0; r < 4; ++r) {
        {
            int rown = wv * 32 + quad * 4 + r;
            int h = gh * 8 + (rown >> 4), w = gw * 16 + (rown & 15);
            size_t base = ((size_t)(b * 64 + h) * 64 + w) * 512 + nh * 32;
            oatt[base + l16]      = (__bf16)(o00[r] * rs0[r]);
            oatt[base + 16 + l16] = (__bf16)(o01[r] * rs0[r]);
        }
        {
            int rown = wv * 32 + 16 + quad * 4 + r;
            int h = gh * 8 + (rown >> 4), w = gw * 16 + (rown & 15);
            size_t base = ((size_t)(b * 64 + h) * 64 + w) * 512 + nh * 32;
            oatt[base + l16]      = (__bf16)(o10[r] * rs1[r]);
            oatt[base + 16 + l16] = (__bf16)(o11[r] * rs1[r]);
        }
    }
}

extern "C" void kernel_launch(void* const* d_in, const int* in_sizes, int n_in,
                              void* d_out, int out_size, void* d_ws, size_t ws_size,
                              hipStream_t stream) {
    const float* x     = (const float*)d_in[0];
    const float* peq   = (const float*)d_in[1];
    const float* pekv  = (const float*)d_in[2];
    const float* mask  = (const float*)d_in[3];
    const float* wq    = (const float*)d_in[4];
    const float* bq    = (const float*)d_in[5];
    const float* wkv   = (const float*)d_in[6];
    const float* bkv   = (const float*)d_in[7];
    const float* wproj = (const float*)d_in[8];
    const float* bproj = (const float*)d_in[9];
    float* out = (float*)d_out;

    char* ws = (char*)d_ws;
    // workspace layout (bytes):
    //   [0, 33554432)            xb (bf16 32768x512)  -- reused as o_attn after GEMM1
    //   [33554432, 35127296)     wqkvT (bf16 1536x512) -- reused as mask flags after GEMM1
    //   [35127296, 35651584)     wpT   (bf16 512x512)
    //   [35651584, 136314880)    qkv   (bf16 [3][16][32768][32])
    __bf16* xb    = (__bf16*)(ws);
    __bf16* oatt  = (__bf16*)(ws);
    __bf16* wqkvT = (__bf16*)(ws + 33554432);
    int*    mflag = (int*)(ws + 33554432);
    __bf16* wpT   = (__bf16*)(ws + 35127296);
    __bf16* qkv   = (__bf16*)(ws + 35651584);

    cast_x_kernel<<<8192, 256, 0, stream>>>((const float4*)x, (bf16x8*)xb);
    transpose_cast_kernel<<<dim3(16, 16), dim3(32, 8), 0, stream>>>(wq, wqkvT, 512, 512);
    transpose_cast_kernel<<<dim3(32, 16), dim3(32, 8), 0, stream>>>(wkv, wqkvT + 512 * 512, 512, 1024);
    transpose_cast_kernel<<<dim3(16, 16), dim3(32, 8), 0, stream>>>(wproj, wpT, 512, 512);

    // qkv: M=32768, N=1536 -> grid 256*12 = 3072 (bm-major per XCD, %8==0)
    gemm128<<<3072, 256, 0, stream>>>(xb, wqkvT, bq, bkv, qkv, 1536, 0);
    mask_flag_kernel<<<32, 256, 0, stream>>>(mask, mflag);
    attn_kernel<<<4096, 256, 0, stream>>>(qkv, peq, pekv, mask, mflag, oatt);
    // proj: M=32768, N=512 -> grid 256*4 = 1024
    gemm128<<<1024, 256, 0, stream>>>(oatt, wpT, bproj, bproj, out, 512, 1);
}